// Round 4
// baseline (379.374 us; speedup 1.0000x reference)
//
#include <hip/hip_runtime.h>

// LSTM B=4096 T=512 IN=14 H=28 OUT=2, fp32 in/out.
// R4: MB=4 batch/block -> grid 1024 -> 4 blocks/CU (4 waves/SIMD) so four
// independent per-block serial chains interleave on each SIMD.
// Per step:
//   phase A: wave g = gate; A = [h|pad] and [x|pad] bf16 rows (rows 0..3 real),
//            4x mfma_f32_16x16x32_bf16, raw preacts -> LDS (q==0 lanes, b128).
//   phase B: 112 threads, one (b,u) element each: merged-rcp gates
//            (5 exp + 2 rcp), c in thread registers, h -> bf16 A-row + f32 copy.
// x pre-converted to bf16 A-layout per 32-step chunk; next chunk's global
// loads held in 7 VGPRs across the chunk (HBM latency fully hidden).

#define T_STEPS 512
#define BATCH   4096
#define IN_F    14
#define HID     28
#define OUT_N   2
#define MB      4                  // batch per block
#define TC      32                 // timesteps per x chunk
#define NCHUNK  (T_STEPS / TC)     // 16
#define HPITCH  40                 // shorts per h row (80 B)
#define XPITCH  32                 // shorts per x row (64 B)
#define PPITCH  12                 // floats per preact row (48 B, 2-way banks)
#define XREGS   ((MB * TC * IN_F) / 256)   // 7

typedef __attribute__((ext_vector_type(8))) short  short8;
typedef __attribute__((ext_vector_type(4))) float  float4v;

#define L1 1.4426950408889634f
#define L2 2.8853900817779268f

__device__ __forceinline__ unsigned short f2bf(float f) {
    union { float f; unsigned int u; } v; v.f = f;
    unsigned int r = (v.u + 0x7FFFu + ((v.u >> 16) & 1u)) >> 16;  // RNE
    return (unsigned short)r;
}

__global__ __launch_bounds__(256, 4)
void lstm_mfma4(const float* __restrict__ x,
                const float* __restrict__ W_ih,
                const float* __restrict__ W_hh,
                const float* __restrict__ b_ih,
                const float* __restrict__ b_hh,
                const float* __restrict__ W_out,
                const float* __restrict__ b_out,
                float* __restrict__ out) {
    __shared__ __align__(16) short h_a[MB][HPITCH];          // bf16 h rows, cols 0..27 (28..31 = 0)
    __shared__ __align__(16) short x_a[2][TC][MB][XPITCH];   // bf16 x rows, cols 0..13 (14..31 = 0)
    __shared__ __align__(16) float pre[4 * HID * PPITCH];    // raw preacts [g][u][b]
    __shared__ float hfin[MB][HID];                          // f32 h for epilogue

    const int tid = threadIdx.x;
    const int wg  = tid >> 6;        // wave = gate (0=i,1=f,2=g,3=o)
    const int l   = tid & 63;
    const int q   = l >> 4;
    const int m   = l & 15;
    const int mr  = m & (MB - 1);    // real batch row (rows MB..15 duplicate)
    const int b0  = blockIdx.x * MB;

    // ---- weights -> VGPR B-fragments; bias for acc init ----
    short8 bfrag[2][2];              // [ktile][ntile]
    float  biasf[2];
    #pragma unroll
    for (int nt = 0; nt < 2; ++nt) {
        const int n   = nt * 16 + m;
        const bool vr = (n < HID);
        const int row = wg * HID + (vr ? n : 0);
        biasf[nt] = vr ? (b_ih[row] + b_hh[row]) : 0.0f;
        #pragma unroll
        for (int kt = 0; kt < 2; ++kt) {
            short8 v;
            #pragma unroll
            for (int j = 0; j < 8; ++j) {
                const int k = q * 8 + j;
                float w = 0.0f;
                if (vr) {
                    if (kt == 0) { if (k < HID)  w = W_hh[row * HID + k]; }
                    else         { if (k < IN_F) w = W_ih[row * IN_F + k]; }
                }
                v[j] = (short)f2bf(w);
            }
            bfrag[kt][nt] = v;
        }
    }

    // ---- zero h rows (h0 = 0 + pads) and x pads ----
    for (int u = tid; u < MB * HPITCH; u += 256) ((short*)h_a)[u] = 0;
    for (int u = tid; u < 2 * TC * MB * XPITCH; u += 256) ((short*)x_a)[u] = 0;

    // ---- prefetch chunk 0 into registers (coalesced) ----
    const float* xbase = x + (long)b0 * T_STEPS * IN_F;
    float xr[XREGS];
    #pragma unroll
    for (int k = 0; k < XREGS; ++k) {
        const int u  = tid + 256 * k;
        const int bb = u / (TC * IN_F);
        const int r  = u - bb * (TC * IN_F);
        xr[k] = xbase[(long)bb * T_STEPS * IN_F + r];
    }
    __syncthreads();   // zero-init visible

    // phase-B element ownership: b = pb (0..3), u = pu (0..27); 112 active threads
    const int pb = tid & (MB - 1);
    const int pu = tid >> 2;
    const bool bact = (pu < HID);
    float c = 0.0f;

    for (int ch = 0; ch < NCHUNK; ++ch) {
        const int buf = ch & 1;
        // convert held registers -> bf16 A-layout for this chunk
        #pragma unroll
        for (int k = 0; k < XREGS; ++k) {
            const int u  = tid + 256 * k;
            const int bb = u / (TC * IN_F);
            const int r  = u - bb * (TC * IN_F);
            const int t  = r / IN_F;
            const int f  = r - t * IN_F;
            x_a[buf][t][bb][f] = (short)f2bf(xr[k]);
        }
        // issue next chunk's global loads (consumed TC steps later)
        if (ch + 1 < NCHUNK) {
            #pragma unroll
            for (int k = 0; k < XREGS; ++k) {
                const int u  = tid + 256 * k;
                const int bb = u / (TC * IN_F);
                const int r  = u - bb * (TC * IN_F);
                xr[k] = xbase[(long)bb * T_STEPS * IN_F + (ch + 1) * TC * IN_F + r];
            }
        }
        __syncthreads();   // x_a[buf] visible

        for (int tt = 0; tt < TC; ++tt) {
            // ---- phase A: raw gate preacts via MFMA ----
            short8 a1 = *(const short8*)&x_a[buf][tt][mr][q * 8];  // no h dependency
            short8 a0 = *(const short8*)&h_a[mr][q * 8];
            float4v acc0 = {biasf[0], biasf[0], biasf[0], biasf[0]};
            float4v acc1 = {biasf[1], biasf[1], biasf[1], biasf[1]};
            acc0 = __builtin_amdgcn_mfma_f32_16x16x32_bf16(a0, bfrag[0][0], acc0, 0, 0, 0);
            acc0 = __builtin_amdgcn_mfma_f32_16x16x32_bf16(a1, bfrag[1][0], acc0, 0, 0, 0);
            acc1 = __builtin_amdgcn_mfma_f32_16x16x32_bf16(a0, bfrag[0][1], acc1, 0, 0, 0);
            acc1 = __builtin_amdgcn_mfma_f32_16x16x32_bf16(a1, bfrag[1][1], acc1, 0, 0, 0);
            // C/D: col = m, row = q*4+r; rows 0..3 (= batch) live in q==0 lanes
            if (q == 0) {
                *(float4v*)&pre[(wg * HID + m) * PPITCH] = acc0;
                if (m < HID - 16)
                    *(float4v*)&pre[(wg * HID + m + 16) * PPITCH] = acc1;
            }
            __syncthreads();   // preacts visible

            // ---- phase B: one element per thread ----
            if (bact) {
                float pi = pre[(0 * HID + pu) * PPITCH + pb];
                float pf = pre[(1 * HID + pu) * PPITCH + pb];
                float pg = pre[(2 * HID + pu) * PPITCH + pb];
                float po = pre[(3 * HID + pu) * PPITCH + pb];
                float ei = __builtin_amdgcn_exp2f(pi * (-L1));
                float ef = __builtin_amdgcn_exp2f(pf * (-L1));
                float eg = __builtin_amdgcn_exp2f(pg * (-L2));
                float eo = __builtin_amdgcn_exp2f(po * (-L1));
                float av = 1.0f + ei, bv = 1.0f + ef, dv = 1.0f + eg, vv = 1.0f + eo;
                float pd  = av * dv;
                float rv  = __builtin_amdgcn_rcpf(pd * bv);
                float sfv = pd * rv;                       // sigma(f)
                float igv = (1.0f - eg) * bv * rv;         // sigma(i)*tanh(g)
                c = fmaf(sfv, c, igv);
                float ec = __builtin_amdgcn_exp2f(c * (-L2));
                float wv = 1.0f + ec;
                float r2 = __builtin_amdgcn_rcpf(vv * wv);
                float h  = (1.0f - ec) * r2;               // sigma(o)*tanh(c)
                h_a[pb][pu]  = (short)f2bf(h);
                hfin[pb][pu] = h;
            }
            __syncthreads();   // h_t visible for next step
        }
    }

    // ---- epilogue: out[b][o] = hfin[b] . W_out[o] + b_out[o] ----
    if (tid < MB * OUT_N) {
        const int o  = tid & 1;
        const int bb = tid >> 1;
        float s = b_out[o];
        #pragma unroll
        for (int u = 0; u < HID; ++u)
            s = fmaf(hfin[bb][u], W_out[o * HID + u], s);
        out[(b0 + bb) * OUT_N + o] = s;
    }
}

extern "C" void kernel_launch(void* const* d_in, const int* in_sizes, int n_in,
                              void* d_out, int out_size, void* d_ws, size_t ws_size,
                              hipStream_t stream) {
    const float* x     = (const float*)d_in[0];
    const float* W_ih  = (const float*)d_in[1];
    const float* W_hh  = (const float*)d_in[2];
    const float* b_ih  = (const float*)d_in[3];
    const float* b_hh  = (const float*)d_in[4];
    const float* W_out = (const float*)d_in[5];
    const float* b_out = (const float*)d_in[6];
    float* out = (float*)d_out;

    lstm_mfma4<<<BATCH / MB, 256, 0, stream>>>(
        x, W_ih, W_hh, b_ih, b_hh, W_out, b_out, out);
}